// Round 1
// baseline (326.929 us; speedup 1.0000x reference)
//
#include <hip/hip_runtime.h>
#include <hip/hip_bf16.h>
#include <math.h>

#define N_  128
#define D_  512
#define L_  512
#define K_  512
#define M_  (N_*D_)   // 65536

typedef __bf16 bf16x8 __attribute__((ext_vector_type(8)));
typedef float  f32x4  __attribute__((ext_vector_type(4)));
typedef unsigned short ushort_t;

// ---------------------------------------------------------------------------
// Kernel 1: bf16 DFT basis (Bc/Bs, [k][l], symmetric) + separable window
// tables: W[d,l] = P[d] + Q[d]*C[l],  P=a*e, Q=-(1-a)*e, e=exp(sigma/511),
// C[l]=cos(2*pi*l/511). Basis reduced exactly via (k*l mod 511), fp32 sincos.
// ---------------------------------------------------------------------------
__global__ void basis_kernel(const float* __restrict__ a,
                             const float* __restrict__ sigma,
                             ushort_t* __restrict__ Bc,
                             ushort_t* __restrict__ Bs,
                             float* __restrict__ P,
                             float* __restrict__ Q,
                             float* __restrict__ C) {
    int idx = blockIdx.x * 256 + threadIdx.x;   // 0 .. 512*512-1
    int r = idx >> 9;    // k
    int c = idx & 511;   // l
    unsigned m = (unsigned)(r * c) % 511u;      // exact periodic reduction
    const float w0 = 6.283185307179586f / 511.0f;
    float sn, cs;
    sincosf((float)m * w0, &sn, &cs);
    __hip_bfloat16 bc = __float2bfloat16(cs);
    __hip_bfloat16 bs = __float2bfloat16(sn);
    ushort_t uc, us;
    __builtin_memcpy(&uc, &bc, 2);
    __builtin_memcpy(&us, &bs, 2);
    Bc[idx] = uc;
    Bs[idx] = us;
    if (idx < 512) {
        float e = expf(sigma[idx] * (1.0f / 511.0f));
        P[idx] = a[idx] * e;
        Q[idx] = -(1.0f - a[idx]) * e;
        C[idx] = cosf((float)idx * w0);
    }
}

static __device__ __forceinline__ unsigned pack_bf16x2(float lo, float hi) {
    __hip_bfloat162 h = __float22bfloat162_rn(make_float2(lo, hi));
    unsigned u;
    __builtin_memcpy(&u, &h, 4);
    return u;   // lo in low 16 bits -> memory order [lo, hi]
}

static __device__ __forceinline__ void load_lds_128(const void* g, void* l) {
    __builtin_amdgcn_global_load_lds(
        (const __attribute__((address_space(1))) unsigned int*)g,
        (__attribute__((address_space(3))) unsigned int*)l,
        16, 0, 0);
}

// ---------------------------------------------------------------------------
// Kernel 2: xw[m][l] = bf16(x[m][l] * (P[d] + Q[d]*C[l])), d = m%512.
// One float4 per thread, consecutive lanes -> consecutive 16B reads / 8B
// writes. 33,554,432 floats / 4 per thread = 8,388,608 threads = 32768 blocks.
// ---------------------------------------------------------------------------
__global__ void prep_kernel(const float* __restrict__ x,
                            const float* __restrict__ P,
                            const float* __restrict__ Q,
                            const float* __restrict__ C,
                            ushort_t* __restrict__ xw) {
    int t = blockIdx.x * 256 + threadIdx.x;     // 0 .. 8388607
    size_t e0 = (size_t)t * 4;
    int row = t >> 7;            // m-row (512 floats = 128 float4 per row)
    int li  = t & 127;           // float4 index within row
    int d   = row & (D_ - 1);
    float4 xv = *(const float4*)(x + e0);
    float4 cv = *(const float4*)(C + li * 4);
    float p = P[d], q = Q[d];
    float w0v = fmaf(q, cv.x, p);
    float w1v = fmaf(q, cv.y, p);
    float w2v = fmaf(q, cv.z, p);
    float w3v = fmaf(q, cv.w, p);
    int2 s;
    s.x = (int)pack_bf16x2(xv.x * w0v, xv.y * w1v);
    s.y = (int)pack_bf16x2(xv.z * w2v, xv.w * w3v);
    *(int2*)(xw + e0) = s;
}

// ---------------------------------------------------------------------------
// Kernel 3: dual-accumulator bf16 MFMA GEMM, BM=128 BN=128 BK=32, 4 waves 2x2
// (each wave 64x64 per trig branch). All staging via global_load_lds(16B)
// with XOR 16B-chunk swizzle (zero bank conflicts, verified round 2).
// Per wave-iter: 32 MFMA : 12 ds_read_b128.
// NEW this round: double-buffered LDS + 2-phase pipeline (T3 minimum):
//   STAGE(next tile) -> ds_read+MFMA(cur) -> one barrier per iter.
// Stage loads get the full MFMA phase to complete before the barrier's
// vmcnt(0) drain, instead of a fully-exposed drain every iteration.
// ---------------------------------------------------------------------------
__global__ __launch_bounds__(256, 2)
void dft_gemm3(const ushort_t* __restrict__ xw,
               const ushort_t* __restrict__ Bc,
               const ushort_t* __restrict__ Bs,
               float* __restrict__ out) {
    // [2] double buffers, each 128x32 bf16 = 8 KB -> 48 KB total
    __shared__ ushort_t sA [2 * 128 * 32];
    __shared__ ushort_t sBc[2 * 128 * 32];
    __shared__ ushort_t sBs[2 * 128 * 32];

    const int b  = blockIdx.x;          // 2048 blocks
    const int ng = b & 3;
    const int mg = b >> 2;
    const int m0 = mg * 128;
    const int n0 = ng * 128;

    const int tid  = threadIdx.x;
    const int w    = tid >> 6;
    const int lane = tid & 63;

    // --- staging: tile = 512 x 16B chunks; 2 issues per buffer per thread ---
    // chunk fc -> row = fc>>2, phys chunk pc = fc&3, logical q = pc^((row>>1)&3)
    const int r0 = tid >> 2;
    const int q0 = (tid & 3) ^ ((r0 >> 1) & 3);
    const int r1 = (256 + tid) >> 2;
    const int q1 = ((256 + tid) & 3) ^ ((r1 >> 1) & 3);

    const ushort_t* aS0  = xw + (size_t)(m0 + r0) * L_ + q0 * 8;
    const ushort_t* aS1  = xw + (size_t)(m0 + r1) * L_ + q1 * 8;
    const ushort_t* bcS0 = Bc + (size_t)(n0 + r0) * L_ + q0 * 8;
    const ushort_t* bcS1 = Bc + (size_t)(n0 + r1) * L_ + q1 * 8;
    const ushort_t* bsS0 = Bs + (size_t)(n0 + r0) * L_ + q0 * 8;
    const ushort_t* bsS1 = Bs + (size_t)(n0 + r1) * L_ + q1 * 8;

    const int wm = w >> 1, wn = w & 1;
    const int ml = lane & 15, quad = lane >> 4;

    int aOff[4], bOff[4];
#pragma unroll
    for (int mi = 0; mi < 4; ++mi) {
        int ar = wm * 64 + mi * 16 + ml;
        int pc = quad ^ ((ar >> 1) & 3);
        aOff[mi] = ar * 32 + pc * 8;
    }
#pragma unroll
    for (int ni = 0; ni < 4; ++ni) {
        int br = wn * 64 + ni * 16 + ml;
        int pc = quad ^ ((br >> 1) & 3);
        bOff[ni] = br * 32 + pc * 8;
    }

    f32x4 acc_c[4][4], acc_s[4][4];
    const f32x4 zero = {0.f, 0.f, 0.f, 0.f};
#pragma unroll
    for (int mi = 0; mi < 4; ++mi)
#pragma unroll
        for (int ni = 0; ni < 4; ++ni) { acc_c[mi][ni] = zero; acc_s[mi][ni] = zero; }

    // stage k-tile kk into buffer buf (6 x 16B per thread = 24 KB total)
#define STAGE(buf, kk)                                                        \
    do {                                                                      \
        const int bo_ = (buf) * 4096;                                         \
        load_lds_128(aS0  + (kk), sA  + bo_ + w * 512);                       \
        load_lds_128(aS1  + (kk), sA  + bo_ + 2048 + w * 512);                \
        load_lds_128(bcS0 + (kk), sBc + bo_ + w * 512);                       \
        load_lds_128(bcS1 + (kk), sBc + bo_ + 2048 + w * 512);                \
        load_lds_128(bsS0 + (kk), sBs + bo_ + w * 512);                       \
        load_lds_128(bsS1 + (kk), sBs + bo_ + 2048 + w * 512);                \
    } while (0)

    auto compute_tile = [&](int buf) {
        const int bo = buf * 4096;
        bf16x8 af[4], bcf[4], bsf[4];
#pragma unroll
        for (int mi = 0; mi < 4; ++mi)
            af[mi] = *(const bf16x8*)&sA[bo + aOff[mi]];
#pragma unroll
        for (int ni = 0; ni < 4; ++ni) {
            bcf[ni] = *(const bf16x8*)&sBc[bo + bOff[ni]];
            bsf[ni] = *(const bf16x8*)&sBs[bo + bOff[ni]];
        }
#pragma unroll
        for (int mi = 0; mi < 4; ++mi)
#pragma unroll
            for (int ni = 0; ni < 4; ++ni) {
                acc_c[mi][ni] = __builtin_amdgcn_mfma_f32_16x16x32_bf16(
                    af[mi], bcf[ni], acc_c[mi][ni], 0, 0, 0);
                acc_s[mi][ni] = __builtin_amdgcn_mfma_f32_16x16x32_bf16(
                    af[mi], bsf[ni], acc_s[mi][ni], 0, 0, 0);
            }
    };

    // prologue: stage k-tile 0 into buffer 0
    STAGE(0, 0);
    __syncthreads();   // compiler-emitted vmcnt(0) drain before barrier

    int cur = 0;
    for (int kk = 32; kk < L_; kk += 32) {
        STAGE(cur ^ 1, kk);    // issue next-tile loads FIRST (overlap w/ MFMA)
        compute_tile(cur);     // ds_read + 32 MFMA on current buffer
        __syncthreads();       // drains vmcnt for next buffer; guards reuse
        cur ^= 1;
    }
    compute_tile(cur);         // last k-tile, no prefetch

#undef STAGE

    // C/D layout: col = lane&15, row = quad*4 + reg (m89/m91-verified)
#pragma unroll
    for (int mi = 0; mi < 4; ++mi)
#pragma unroll
        for (int ni = 0; ni < 4; ++ni) {
#pragma unroll
            for (int r = 0; r < 4; ++r) {
                float cv = acc_c[mi][ni][r];
                float sv = acc_s[mi][ni][r];
                int row = m0 + wm * 64 + mi * 16 + quad * 4 + r;
                int col = n0 + wn * 64 + ni * 16 + ml;
                out[(size_t)row * K_ + col] = sqrtf(cv * cv + sv * sv);
            }
        }
}

extern "C" void kernel_launch(void* const* d_in, const int* in_sizes, int n_in,
                              void* d_out, int out_size, void* d_ws, size_t ws_size,
                              hipStream_t stream) {
    (void)in_sizes; (void)n_in; (void)out_size; (void)ws_size;
    const float* x     = (const float*)d_in[0];
    const float* a     = (const float*)d_in[1];
    const float* sigma = (const float*)d_in[2];
    float* out = (float*)d_out;

    // ws: Bc (512KB) | Bs (512KB) | P (2KB) | Q (2KB) | C (2KB) | xw (67.1MB)
    ushort_t* Bc = (ushort_t*)d_ws;
    ushort_t* Bs = Bc + 512 * 512;
    float*    P  = (float*)(Bs + 512 * 512);
    float*    Q  = P + 512;
    float*    C  = Q + 512;
    ushort_t* xw = (ushort_t*)(C + 512);

    basis_kernel<<<dim3(1024), dim3(256), 0, stream>>>(a, sigma, Bc, Bs, P, Q, C);
    prep_kernel<<<dim3(32768), dim3(256), 0, stream>>>(x, P, Q, C, xw);
    dft_gemm3<<<dim3(2048), dim3(256), 0, stream>>>(xw, Bc, Bs, out);
}